// Round 8
// baseline (201.203 us; speedup 1.0000x reference)
//
#include <hip/hip_runtime.h>
#include <hip/hip_bf16.h>

#define NPTS 12288
#define DD 128
#define CHUNKS 16
#define CHW (NPTS / CHUNKS)   // 768 cols per chunk
#define TILES (CHW / 64)      // 12 col-tiles of 64
#define NBG (NPTS / 128)      // 96 col-partial groups (128 rows each)

// descriptors pre-scaled by sqrt(10 * log2(e)) so MFMA result a = S*log2(e);
// then e^S = exp2(a) directly and argmax keys come from bits(exp2(a)).
#define PRESCALE 3.79828262f

typedef short bf16x8 __attribute__((ext_vector_type(8)));
typedef float f32x4 __attribute__((ext_vector_type(4)));

__device__ __forceinline__ float fast_exp2(float x) {
#if defined(__has_builtin)
#if __has_builtin(__builtin_amdgcn_exp2f)
  return __builtin_amdgcn_exp2f(x);
#else
  return exp2f(x);
#endif
#else
  return exp2f(x);
#endif
}

__device__ __forceinline__ short f2bf(float f) {  // RNE f32 -> bf16
  unsigned u = __float_as_uint(f);
  u += 0x7FFFu + ((u >> 16) & 1u);
  return (short)(u >> 16);
}

__device__ __forceinline__ unsigned umax(unsigned a, unsigned b) { return a > b ? a : b; }

// ---------------- pure conversion: f32 -> prescaled bf16 ----------------
__global__ void k_conv(const float* __restrict__ d0, const float* __restrict__ d1,
                       short* __restrict__ o0, short* __restrict__ o1) {
  unsigned t = blockIdx.x * 256u + threadIdx.x;
  const unsigned half = (NPTS * DD) / 4;
  const float* src; short* dst; unsigned g;
  if (t < half) { src = d0; dst = o0; g = t; }
  else          { src = d1; dst = o1; g = t - half; }
  float4 v = *(const float4*)(src + (size_t)g * 4);
  short4 r;
  r.x = f2bf(v.x * PRESCALE); r.y = f2bf(v.y * PRESCALE);
  r.z = f2bf(v.z * PRESCALE); r.w = f2bf(v.w * PRESCALE);
  *(short4*)(dst + (size_t)g * 4) = r;
}

// ---------------- main fused kernel ----------------
// block = (bandgroup of 128 rows, chunk): 4 waves, wave w owns rows
// bg*128 + w*32 .. +31 (32x64 wave tile: acc 32 AGPR + af 32 VGPR, 116 regs
// total -> 4 waves/SIMD fits the 128-reg budget of __launch_bounds__(256,4);
// LDS 36.9KB -> 4 blocks/CU = 147KB < 160KB).
// B staged global->LDS async (double buffer 2x16KB: linear LDS dest,
// pre-swizzled global source, swizzled ds_read - rule 21).
// Col partials combined across the block's 4 waves in LDS per tile
// (crLds double-buffered by t&1), wave 0 stores one uint2 per column.
// Argmax keys are positive floats (bits(exp2(a)) masked | index-complement);
// float max == uint max for positives -> nested fmaxf fuses to v_max3_f32.
// C-frag: col = lane&15, row = (lane>>4)*4 + reg (m89/m91, verified R1-R7).
__launch_bounds__(256, 4)
__global__ void k_main(const short* __restrict__ d0b, const short* __restrict__ d1b,
                       uint2* __restrict__ colKV, uint2* __restrict__ rowKV) {
  __shared__ __align__(16) char bLds[2][16384];
  __shared__ uint2 crLds[2][4][64];
  const int widx = threadIdx.x >> 6;
  const int lane = threadIdx.x & 63;
  const int lo = lane & 15, hi = lane >> 4;
  const int chunk = blockIdx.x & (CHUNKS - 1);
  const int bg = blockIdx.x >> 4;                  // 0..95
  const int row0 = bg * 128 + widx * 32;
  const int cbase = chunk * CHW;

  const char* btile0 = (const char*)(d1b + (size_t)cbase * DD);  // tile t at +t*16384

  // stage helper: wave w writes LDS [w*4096, +4096) linearly in 4 rounds;
  // global source pre-swizzled so lds[linear] = tile[linear^swz].
  #define STAGE(tt, bb) do {                                                   \
    const char* gsrc_ = btile0 + (size_t)(tt) * 16384;                         \
    _Pragma("unroll")                                                          \
    for (int it_ = 0; it_ < 4; it_++) {                                        \
      int L_ = (widx << 12) + (it_ << 10) + (lane << 4);                       \
      int so_ = L_ ^ (((L_ >> 8) & 7) << 4);                                   \
      __builtin_amdgcn_global_load_lds((const void*)(gsrc_ + so_),             \
          (void*)(&bLds[bb][(widx << 12) + (it_ << 10)]), 16, 0, 0);           \
    }                                                                          \
  } while (0)

  // A fragments for this wave's 32 rows, all of K=128 (held whole kernel)
  bf16x8 af[2][4];
  #pragma unroll
  for (int i = 0; i < 2; i++)
    #pragma unroll
    for (int kk = 0; kk < 4; kk++)
      af[i][kk] = *(const bf16x8*)(d0b + (size_t)(row0 + i * 16 + lo) * DD + kk * 32 + hi * 8);

  float rowsum[2][4], rowkeyf[2][4];
  #pragma unroll
  for (int i = 0; i < 2; i++)
    #pragma unroll
    for (int r = 0; r < 4; r++) {
      rowsum[i][r] = 0.f;
      rowkeyf[i][r] = 0.f;
    }
  const unsigned rcbase = 0x3FFFu - (unsigned)(row0 + hi * 4);
  const int axor = (lo & 7) << 4;                  // lane-constant read swizzle

  STAGE(0, 0);
  __syncthreads();   // vmcnt(0) drain: tile 0 resident

  #pragma unroll 1
  for (int t = 0; t < TILES; t++) {
    const int cur = t & 1;
    if (t + 1 < TILES) STAGE(t + 1, cur ^ 1);

    f32x4 acc[2][4];
    #pragma unroll
    for (int i = 0; i < 2; i++)
      #pragma unroll
      for (int j = 0; j < 4; j++)
        acc[i][j] = (f32x4){0.f, 0.f, 0.f, 0.f};

    const char* bbuf = &bLds[cur][0];
    #pragma unroll
    for (int kk = 0; kk < 4; kk++) {
      bf16x8 bfr[4];
      #pragma unroll
      for (int j = 0; j < 4; j++) {
        int bbyte = (((j << 4) + lo) << 8) + (kk << 6) + (hi << 4);
        bbyte ^= axor;
        bfr[j] = *(const bf16x8*)(bbuf + bbyte);
      }
      #pragma unroll
      for (int j = 0; j < 4; j++)
        #pragma unroll
        for (int i = 0; i < 2; i++)
          acc[i][j] = __builtin_amdgcn_mfma_f32_16x16x32_bf16(af[i][kk], bfr[j], acc[i][j], 0, 0, 0);
    }

    // fused epilogue: e = e^S = exp2(a); float-typed keys (max3-fusable)
    const int ct = cbase + t * 64;
    #pragma unroll
    for (int j = 0; j < 4; j++) {
      float colsum = 0.f;
      float colkeyf = 0.f;
      const unsigned ccomp = 0x3FFFu - (unsigned)(ct + j * 16 + lo);
      #pragma unroll
      for (int i = 0; i < 2; i++)
        #pragma unroll
        for (int r = 0; r < 4; r++) {
          float e = fast_exp2(acc[i][j][r]);
          unsigned tb = __float_as_uint(e) & 0xFFFFC000u;
          rowkeyf[i][r] = fmaxf(rowkeyf[i][r], __uint_as_float(tb | ccomp));
          colkeyf = fmaxf(colkeyf, __uint_as_float(tb | (rcbase - (unsigned)(i * 16 + r))));
          rowsum[i][r] += e;
          colsum += e;
        }
      colsum += __shfl_xor(colsum, 16, 64);
      colsum += __shfl_xor(colsum, 32, 64);
      colkeyf = fmaxf(colkeyf, __shfl_xor(colkeyf, 16, 64));
      colkeyf = fmaxf(colkeyf, __shfl_xor(colkeyf, 32, 64));
      if (hi == 0)
        crLds[cur][widx][j * 16 + lo] = make_uint2(__float_as_uint(colkeyf), __float_as_uint(colsum));
    }

    __syncthreads();   // crLds visible; bLds[cur^1] staged; all done with buf[cur]

    // wave 0: combine 4 waves' col partials, one store per column
    if (threadIdx.x < 64) {
      int c = threadIdx.x;
      uint2 p0 = crLds[cur][0][c], p1 = crLds[cur][1][c];
      uint2 p2 = crLds[cur][2][c], p3 = crLds[cur][3][c];
      float s = __uint_as_float(p0.y) + __uint_as_float(p1.y) +
                __uint_as_float(p2.y) + __uint_as_float(p3.y);
      float k = fmaxf(fmaxf(__uint_as_float(p0.x), __uint_as_float(p1.x)),
                      fmaxf(__uint_as_float(p2.x), __uint_as_float(p3.x)));
      colKV[(size_t)bg * NPTS + ct + c] = make_uint2(__float_as_uint(k), __float_as_uint(s));
    }
  }

  // row partials: reduce over lo bits (cols), lanes with lo==0 write
  #pragma unroll
  for (int i = 0; i < 2; i++)
    #pragma unroll
    for (int r = 0; r < 4; r++) {
      float s = rowsum[i][r];
      float k = rowkeyf[i][r];
      s += __shfl_xor(s, 1, 64); s += __shfl_xor(s, 2, 64);
      s += __shfl_xor(s, 4, 64); s += __shfl_xor(s, 8, 64);
      k = fmaxf(k, __shfl_xor(k, 1, 64));
      k = fmaxf(k, __shfl_xor(k, 2, 64));
      k = fmaxf(k, __shfl_xor(k, 4, 64));
      k = fmaxf(k, __shfl_xor(k, 8, 64));
      if (lo == 0) {
        int row = row0 + i * 16 + hi * 4 + r;
        rowKV[(size_t)chunk * NPTS + row] = make_uint2(__float_as_uint(k), __float_as_uint(s));
      }
    }
  #undef STAGE
}

// ---------------- fused reduce (+ exact positive dots): blocks 0..47 cols, 48..95 rows ----
__global__ void k_red(const uint2* __restrict__ colKV, const uint2* __restrict__ rowKV,
                      const float* __restrict__ d0, const float* __restrict__ d1,
                      const int* __restrict__ c0, const int* __restrict__ c1,
                      unsigned* __restrict__ best0, unsigned* __restrict__ best1,
                      float* __restrict__ l0part, float* __restrict__ l1part) {
  float v;
  if (blockIdx.x < 48) {
    int m = blockIdx.x * 256 + threadIdx.x;
    float s = 0.f; unsigned k = 0u;
    #pragma unroll 8
    for (int b = 0; b < NBG; b++) {
      uint2 kv = colKV[(size_t)b * NPTS + m];
      s += __uint_as_float(kv.y);
      k = umax(k, kv.x);
    }
    best1[m] = 0x3FFFu - (k & 0x3FFFu);
    int cc = c1[m];
    int i = cc > 0 ? cc : 0;
    const float4* pa = (const float4*)(d0 + (size_t)i * DD);
    const float4* pb = (const float4*)(d1 + (size_t)m * DD);
    float dot = 0.f;
    #pragma unroll 8
    for (int q = 0; q < DD / 4; q++) {
      float4 a = pa[q], b = pb[q];
      dot += a.x * b.x + a.y * b.y + a.z * b.z + a.w * b.w;
    }
    v = (cc >= 0) ? (logf(s) - 10.0f * dot) : 0.f;
  } else {
    int n = (blockIdx.x - 48) * 256 + threadIdx.x;
    float s = 0.f; unsigned k = 0u;
    #pragma unroll
    for (int c = 0; c < CHUNKS; c++) {
      uint2 kv = rowKV[(size_t)c * NPTS + n];
      s += __uint_as_float(kv.y);
      k = umax(k, kv.x);
    }
    best0[n] = 0x3FFFu - (k & 0x3FFFu);
    int cc = c0[n];
    int i = cc > 0 ? cc : 0;
    const float4* pa = (const float4*)(d0 + (size_t)n * DD);
    const float4* pb = (const float4*)(d1 + (size_t)i * DD);
    float dot = 0.f;
    #pragma unroll 8
    for (int q = 0; q < DD / 4; q++) {
      float4 a = pa[q], b = pb[q];
      dot += a.x * b.x + a.y * b.y + a.z * b.z + a.w * b.w;
    }
    v = (cc >= 0) ? (logf(s) - 10.0f * dot) : 0.f;
  }
  __shared__ float red[256];
  red[threadIdx.x] = v; __syncthreads();
  for (int st = 128; st > 0; st >>= 1) {
    if (threadIdx.x < st) red[threadIdx.x] += red[threadIdx.x + st];
    __syncthreads();
  }
  if (threadIdx.x == 0) {
    if (blockIdx.x < 48) l1part[blockIdx.x] = red[0];
    else                 l0part[blockIdx.x - 48] = red[0];
  }
}

// ---------------- stats partials: mutual-NN precision/recall counts (48 blocks) ----------
__global__ void k_stats(const int* __restrict__ c0, const int* __restrict__ c1,
                        const float* __restrict__ lg0, const float* __restrict__ lg1,
                        const unsigned* __restrict__ best0, const unsigned* __restrict__ best1,
                        int4* __restrict__ statpart) {
  int n = blockIdx.x * 256 + threadIdx.x;
  int cc = c0[n];
  bool m0 = cc >= 0;
  int b0 = (int)best0[n];
  bool mutual = ((int)best1[b0] == n);
  bool pred = mutual && (lg0[n] >= 0.f) && (lg1[b0] >= 0.f);
  int4 v;
  v.x = m0 ? 1 : 0;                               // m0 count
  v.y = (c1[n] >= 0) ? 1 : 0;                     // m1 count
  v.z = (pred && m0 && b0 == cc) ? 1 : 0;         // tp
  v.w = pred ? 1 : 0;                             // predicted
  __shared__ int4 red[256];
  red[threadIdx.x] = v; __syncthreads();
  for (int st = 128; st > 0; st >>= 1) {
    if (threadIdx.x < st) {
      int4 o = red[threadIdx.x + st];
      red[threadIdx.x].x += o.x; red[threadIdx.x].y += o.y;
      red[threadIdx.x].z += o.z; red[threadIdx.x].w += o.w;
    }
    __syncthreads();
  }
  if (threadIdx.x == 0) statpart[blockIdx.x] = red[0];
}

// ---------------- final: combine 48 partials of everything ----------------
__global__ void k_final(const float* __restrict__ l0part, const float* __restrict__ l1part,
                        const int4* __restrict__ statpart, float* __restrict__ out) {
  const int tid = threadIdx.x;   // 64 threads
  float l0s = 0.f, l1s = 0.f;
  int4 st = make_int4(0, 0, 0, 0);
  if (tid < 48) {
    l0s = l0part[tid]; l1s = l1part[tid];
    st = statpart[tid];
  }
  #pragma unroll
  for (int off = 32; off >= 1; off >>= 1) {
    l0s += __shfl_down(l0s, off, 64);
    l1s += __shfl_down(l1s, off, 64);
    st.x += __shfl_down(st.x, off, 64);
    st.y += __shfl_down(st.y, off, 64);
    st.z += __shfl_down(st.z, off, 64);
    st.w += __shfl_down(st.w, off, 64);
  }
  if (tid == 0) {
    int M0 = st.x > 0 ? st.x : 1;
    int M1 = st.y > 0 ? st.y : 1;
    int PR = st.w > 0 ? st.w : 1;
    out[0] = l0s / (float)M0;
    out[1] = l1s / (float)M1;
    out[2] = (float)st.z / (float)PR;
    out[3] = (float)st.z / (float)M0;
  }
}

extern "C" void kernel_launch(void* const* d_in, const int* in_sizes, int n_in,
                              void* d_out, int out_size, void* d_ws, size_t ws_size,
                              hipStream_t stream) {
  const float* desc0 = (const float*)d_in[0];
  const float* desc1 = (const float*)d_in[1];
  const int* corr0   = (const int*)d_in[2];
  const int* corr1   = (const int*)d_in[3];
  const float* lg0   = (const float*)d_in[4];
  const float* lg1   = (const float*)d_in[5];
  float* out = (float*)d_out;

  char* w = (char*)d_ws;
  short* d0b   = (short*)(w);                   // 3,145,728 B
  short* d1b   = (short*)(w + 3145728);         // 3,145,728 B
  uint2* colKV = (uint2*)(w + 6291456);         //  9,437,184 B  [96][12288]
  uint2* rowKV = (uint2*)(w + 15728640);        //  1,572,864 B  [16][12288]
  unsigned* best0 = (unsigned*)(w + 17301504);  //     49,152 B
  unsigned* best1 = (unsigned*)(w + 17350656);  //     49,152 B
  float* l0part = (float*)(w + 17399808);       //        192 B
  float* l1part = (float*)(w + 17400000);       //        192 B
  int4* statpart = (int4*)(w + 17400192);       //        768 B

  k_conv<<<3072, 256, 0, stream>>>(desc0, desc1, d0b, d1b);
  k_main<<<1536, 256, 0, stream>>>(d0b, d1b, colKV, rowKV);
  k_red<<<96, 256, 0, stream>>>(colKV, rowKV, desc0, desc1, corr0, corr1, best0, best1, l0part, l1part);
  k_stats<<<48, 256, 0, stream>>>(corr0, corr1, lg0, lg1, best0, best1, statpart);
  k_final<<<1, 64, 0, stream>>>(l0part, l1part, statpart, out);
}

// Round 9
// 103.983 us; speedup vs baseline: 1.9350x; 1.9350x over previous
//
#include <hip/hip_runtime.h>
#include <hip/hip_bf16.h>

#define NPTS 12288
#define DD 128
#define CHUNKS 16
#define CHW (NPTS / CHUNKS)   // 768 cols per chunk
#define TILES (CHW / 64)      // 12 col-tiles of 64
#define NBG (NPTS / 128)      // 96 col-partial groups (128 rows each)

// descriptors pre-scaled by sqrt(10 * log2(e)) so MFMA result a = S*log2(e);
// then e^S = exp2(a) directly and argmax keys come from bits(exp2(a)).
#define PRESCALE 3.79828262f

typedef short bf16x8 __attribute__((ext_vector_type(8)));
typedef float f32x4 __attribute__((ext_vector_type(4)));

__device__ __forceinline__ float fast_exp2(float x) {
#if defined(__has_builtin)
#if __has_builtin(__builtin_amdgcn_exp2f)
  return __builtin_amdgcn_exp2f(x);
#else
  return exp2f(x);
#endif
#else
  return exp2f(x);
#endif
}

__device__ __forceinline__ short f2bf(float f) {  // RNE f32 -> bf16
  unsigned u = __float_as_uint(f);
  u += 0x7FFFu + ((u >> 16) & 1u);
  return (short)(u >> 16);
}

__device__ __forceinline__ unsigned umax(unsigned a, unsigned b) { return a > b ? a : b; }

// ---------------- pure conversion: f32 -> prescaled bf16 ----------------
__global__ void k_conv(const float* __restrict__ d0, const float* __restrict__ d1,
                       short* __restrict__ o0, short* __restrict__ o1) {
  unsigned t = blockIdx.x * 256u + threadIdx.x;
  const unsigned half = (NPTS * DD) / 4;
  const float* src; short* dst; unsigned g;
  if (t < half) { src = d0; dst = o0; g = t; }
  else          { src = d1; dst = o1; g = t - half; }
  float4 v = *(const float4*)(src + (size_t)g * 4);
  short4 r;
  r.x = f2bf(v.x * PRESCALE); r.y = f2bf(v.y * PRESCALE);
  r.z = f2bf(v.z * PRESCALE); r.w = f2bf(v.w * PRESCALE);
  *(short4*)(dst + (size_t)g * 4) = r;
}

// ---------------- main fused kernel ----------------
// block = (bandgroup of 128 rows, chunk): 4 waves, wave w owns rows
// bg*128 + w*32 .. +31. 32x64 wave tile: acc 32 AGPR + af 32 VGPR; codegen
// (R7-proven): 84 VGPR + 32 AGPR, zero spill at __launch_bounds__(256,3).
// DO NOT raise to (256,4): R8 showed the allocator squeezes to 64 VGPR and
// spills (FETCH 14.6 -> 167 MB, 2x slower). (256,3) is the proven optimum.
// B staged global->LDS async (double buffer 2x16KB: linear LDS dest,
// pre-swizzled global source, swizzled ds_read - rule 21).
// Col partials combined across the block's 4 waves in LDS per tile
// (crLds double-buffered by t&1); each wave stores 16 columns (lane<16).
// Argmax keys are positive floats (bits(exp2(a)) masked | index-complement);
// float max == uint max for positives -> nested fmaxf fuses to v_max3_f32.
// C-frag: col = lane&15, row = (lane>>4)*4 + reg (m89/m91, verified R1-R8).
__launch_bounds__(256, 3)
__global__ void k_main(const short* __restrict__ d0b, const short* __restrict__ d1b,
                       uint2* __restrict__ colKV, uint2* __restrict__ rowKV) {
  __shared__ __align__(16) char bLds[2][16384];
  __shared__ uint2 crLds[2][4][64];
  const int widx = threadIdx.x >> 6;
  const int lane = threadIdx.x & 63;
  const int lo = lane & 15, hi = lane >> 4;
  const int chunk = blockIdx.x & (CHUNKS - 1);
  const int bg = blockIdx.x >> 4;                  // 0..95
  const int row0 = bg * 128 + widx * 32;
  const int cbase = chunk * CHW;

  const char* btile0 = (const char*)(d1b + (size_t)cbase * DD);  // tile t at +t*16384

  // stage helper: wave w writes LDS [w*4096, +4096) linearly in 4 rounds;
  // global source pre-swizzled so lds[linear] = tile[linear^swz].
  #define STAGE(tt, bb) do {                                                   \
    const char* gsrc_ = btile0 + (size_t)(tt) * 16384;                         \
    _Pragma("unroll")                                                          \
    for (int it_ = 0; it_ < 4; it_++) {                                        \
      int L_ = (widx << 12) + (it_ << 10) + (lane << 4);                       \
      int so_ = L_ ^ (((L_ >> 8) & 7) << 4);                                   \
      __builtin_amdgcn_global_load_lds((const void*)(gsrc_ + so_),             \
          (void*)(&bLds[bb][(widx << 12) + (it_ << 10)]), 16, 0, 0);           \
    }                                                                          \
  } while (0)

  // A fragments for this wave's 32 rows, all of K=128 (held whole kernel)
  bf16x8 af[2][4];
  #pragma unroll
  for (int i = 0; i < 2; i++)
    #pragma unroll
    for (int kk = 0; kk < 4; kk++)
      af[i][kk] = *(const bf16x8*)(d0b + (size_t)(row0 + i * 16 + lo) * DD + kk * 32 + hi * 8);

  float rowsum[2][4], rowkeyf[2][4];
  #pragma unroll
  for (int i = 0; i < 2; i++)
    #pragma unroll
    for (int r = 0; r < 4; r++) {
      rowsum[i][r] = 0.f;
      rowkeyf[i][r] = 0.f;
    }
  const unsigned rcbase = 0x3FFFu - (unsigned)(row0 + hi * 4);
  const int axor = (lo & 7) << 4;                  // lane-constant read swizzle

  STAGE(0, 0);
  __syncthreads();   // vmcnt(0) drain: tile 0 resident

  #pragma unroll 1
  for (int t = 0; t < TILES; t++) {
    const int cur = t & 1;
    if (t + 1 < TILES) STAGE(t + 1, cur ^ 1);

    f32x4 acc[2][4];
    #pragma unroll
    for (int i = 0; i < 2; i++)
      #pragma unroll
      for (int j = 0; j < 4; j++)
        acc[i][j] = (f32x4){0.f, 0.f, 0.f, 0.f};

    const char* bbuf = &bLds[cur][0];
    #pragma unroll
    for (int kk = 0; kk < 4; kk++) {
      bf16x8 bfr[4];
      #pragma unroll
      for (int j = 0; j < 4; j++) {
        int bbyte = (((j << 4) + lo) << 8) + (kk << 6) + (hi << 4);
        bbyte ^= axor;
        bfr[j] = *(const bf16x8*)(bbuf + bbyte);
      }
      #pragma unroll
      for (int j = 0; j < 4; j++)
        #pragma unroll
        for (int i = 0; i < 2; i++)
          acc[i][j] = __builtin_amdgcn_mfma_f32_16x16x32_bf16(af[i][kk], bfr[j], acc[i][j], 0, 0, 0);
    }

    // fused epilogue: e = e^S = exp2(a); float-typed keys (max3-fusable)
    const int ct = cbase + t * 64;
    #pragma unroll
    for (int j = 0; j < 4; j++) {
      float colsum = 0.f;
      float colkeyf = 0.f;
      const unsigned ccomp = 0x3FFFu - (unsigned)(ct + j * 16 + lo);
      #pragma unroll
      for (int i = 0; i < 2; i++)
        #pragma unroll
        for (int r = 0; r < 4; r++) {
          float e = fast_exp2(acc[i][j][r]);
          unsigned tb = __float_as_uint(e) & 0xFFFFC000u;
          rowkeyf[i][r] = fmaxf(rowkeyf[i][r], __uint_as_float(tb | ccomp));
          colkeyf = fmaxf(colkeyf, __uint_as_float(tb | (rcbase - (unsigned)(i * 16 + r))));
          rowsum[i][r] += e;
          colsum += e;
        }
      colsum += __shfl_xor(colsum, 16, 64);
      colsum += __shfl_xor(colsum, 32, 64);
      colkeyf = fmaxf(colkeyf, __shfl_xor(colkeyf, 16, 64));
      colkeyf = fmaxf(colkeyf, __shfl_xor(colkeyf, 32, 64));
      if (hi == 0)
        crLds[cur][widx][j * 16 + lo] = make_uint2(__float_as_uint(colkeyf), __float_as_uint(colsum));
    }

    __syncthreads();   // crLds visible; bLds[cur^1] staged; all done with buf[cur]

    // combine 4 waves' col partials; wave w handles its own 16 columns
    if (lo < 16 && hi == 0) { }  // (no-op: keep structure clear)
    if (lane < 16) {
      int c = widx * 16 + lane;
      uint2 p0 = crLds[cur][0][c], p1 = crLds[cur][1][c];
      uint2 p2 = crLds[cur][2][c], p3 = crLds[cur][3][c];
      float s = __uint_as_float(p0.y) + __uint_as_float(p1.y) +
                __uint_as_float(p2.y) + __uint_as_float(p3.y);
      float k = fmaxf(fmaxf(__uint_as_float(p0.x), __uint_as_float(p1.x)),
                      fmaxf(__uint_as_float(p2.x), __uint_as_float(p3.x)));
      colKV[(size_t)bg * NPTS + ct + c] = make_uint2(__float_as_uint(k), __float_as_uint(s));
    }
  }

  // row partials: reduce over lo bits (cols), lanes with lo==0 write
  #pragma unroll
  for (int i = 0; i < 2; i++)
    #pragma unroll
    for (int r = 0; r < 4; r++) {
      float s = rowsum[i][r];
      float k = rowkeyf[i][r];
      s += __shfl_xor(s, 1, 64); s += __shfl_xor(s, 2, 64);
      s += __shfl_xor(s, 4, 64); s += __shfl_xor(s, 8, 64);
      k = fmaxf(k, __shfl_xor(k, 1, 64));
      k = fmaxf(k, __shfl_xor(k, 2, 64));
      k = fmaxf(k, __shfl_xor(k, 4, 64));
      k = fmaxf(k, __shfl_xor(k, 8, 64));
      if (lo == 0) {
        int row = row0 + i * 16 + hi * 4 + r;
        rowKV[(size_t)chunk * NPTS + row] = make_uint2(__float_as_uint(k), __float_as_uint(s));
      }
    }
  #undef STAGE
}

// ---------------- fused reduce (+ exact positive dots): blocks 0..47 cols, 48..95 rows ----
__global__ void k_red(const uint2* __restrict__ colKV, const uint2* __restrict__ rowKV,
                      const float* __restrict__ d0, const float* __restrict__ d1,
                      const int* __restrict__ c0, const int* __restrict__ c1,
                      unsigned* __restrict__ best0, unsigned* __restrict__ best1,
                      float* __restrict__ l0part, float* __restrict__ l1part) {
  float v;
  if (blockIdx.x < 48) {
    int m = blockIdx.x * 256 + threadIdx.x;
    float s = 0.f; unsigned k = 0u;
    #pragma unroll 8
    for (int b = 0; b < NBG; b++) {
      uint2 kv = colKV[(size_t)b * NPTS + m];
      s += __uint_as_float(kv.y);
      k = umax(k, kv.x);
    }
    best1[m] = 0x3FFFu - (k & 0x3FFFu);
    int cc = c1[m];
    int i = cc > 0 ? cc : 0;
    const float4* pa = (const float4*)(d0 + (size_t)i * DD);
    const float4* pb = (const float4*)(d1 + (size_t)m * DD);
    float dot = 0.f;
    #pragma unroll 8
    for (int q = 0; q < DD / 4; q++) {
      float4 a = pa[q], b = pb[q];
      dot += a.x * b.x + a.y * b.y + a.z * b.z + a.w * b.w;
    }
    v = (cc >= 0) ? (logf(s) - 10.0f * dot) : 0.f;
  } else {
    int n = (blockIdx.x - 48) * 256 + threadIdx.x;
    float s = 0.f; unsigned k = 0u;
    #pragma unroll
    for (int c = 0; c < CHUNKS; c++) {
      uint2 kv = rowKV[(size_t)c * NPTS + n];
      s += __uint_as_float(kv.y);
      k = umax(k, kv.x);
    }
    best0[n] = 0x3FFFu - (k & 0x3FFFu);
    int cc = c0[n];
    int i = cc > 0 ? cc : 0;
    const float4* pa = (const float4*)(d0 + (size_t)n * DD);
    const float4* pb = (const float4*)(d1 + (size_t)i * DD);
    float dot = 0.f;
    #pragma unroll 8
    for (int q = 0; q < DD / 4; q++) {
      float4 a = pa[q], b = pb[q];
      dot += a.x * b.x + a.y * b.y + a.z * b.z + a.w * b.w;
    }
    v = (cc >= 0) ? (logf(s) - 10.0f * dot) : 0.f;
  }
  __shared__ float red[256];
  red[threadIdx.x] = v; __syncthreads();
  for (int st = 128; st > 0; st >>= 1) {
    if (threadIdx.x < st) red[threadIdx.x] += red[threadIdx.x + st];
    __syncthreads();
  }
  if (threadIdx.x == 0) {
    if (blockIdx.x < 48) l1part[blockIdx.x] = red[0];
    else                 l0part[blockIdx.x - 48] = red[0];
  }
}

// ---------------- stats partials: mutual-NN precision/recall counts (48 blocks) ----------
__global__ void k_stats(const int* __restrict__ c0, const int* __restrict__ c1,
                        const float* __restrict__ lg0, const float* __restrict__ lg1,
                        const unsigned* __restrict__ best0, const unsigned* __restrict__ best1,
                        int4* __restrict__ statpart) {
  int n = blockIdx.x * 256 + threadIdx.x;
  int cc = c0[n];
  bool m0 = cc >= 0;
  int b0 = (int)best0[n];
  bool mutual = ((int)best1[b0] == n);
  bool pred = mutual && (lg0[n] >= 0.f) && (lg1[b0] >= 0.f);
  int4 v;
  v.x = m0 ? 1 : 0;                               // m0 count
  v.y = (c1[n] >= 0) ? 1 : 0;                     // m1 count
  v.z = (pred && m0 && b0 == cc) ? 1 : 0;         // tp
  v.w = pred ? 1 : 0;                             // predicted
  __shared__ int4 red[256];
  red[threadIdx.x] = v; __syncthreads();
  for (int st = 128; st > 0; st >>= 1) {
    if (threadIdx.x < st) {
      int4 o = red[threadIdx.x + st];
      red[threadIdx.x].x += o.x; red[threadIdx.x].y += o.y;
      red[threadIdx.x].z += o.z; red[threadIdx.x].w += o.w;
    }
    __syncthreads();
  }
  if (threadIdx.x == 0) statpart[blockIdx.x] = red[0];
}

// ---------------- final: combine 48 partials of everything ----------------
__global__ void k_final(const float* __restrict__ l0part, const float* __restrict__ l1part,
                        const int4* __restrict__ statpart, float* __restrict__ out) {
  const int tid = threadIdx.x;   // 64 threads
  float l0s = 0.f, l1s = 0.f;
  int4 st = make_int4(0, 0, 0, 0);
  if (tid < 48) {
    l0s = l0part[tid]; l1s = l1part[tid];
    st = statpart[tid];
  }
  #pragma unroll
  for (int off = 32; off >= 1; off >>= 1) {
    l0s += __shfl_down(l0s, off, 64);
    l1s += __shfl_down(l1s, off, 64);
    st.x += __shfl_down(st.x, off, 64);
    st.y += __shfl_down(st.y, off, 64);
    st.z += __shfl_down(st.z, off, 64);
    st.w += __shfl_down(st.w, off, 64);
  }
  if (tid == 0) {
    int M0 = st.x > 0 ? st.x : 1;
    int M1 = st.y > 0 ? st.y : 1;
    int PR = st.w > 0 ? st.w : 1;
    out[0] = l0s / (float)M0;
    out[1] = l1s / (float)M1;
    out[2] = (float)st.z / (float)PR;
    out[3] = (float)st.z / (float)M0;
  }
}

extern "C" void kernel_launch(void* const* d_in, const int* in_sizes, int n_in,
                              void* d_out, int out_size, void* d_ws, size_t ws_size,
                              hipStream_t stream) {
  const float* desc0 = (const float*)d_in[0];
  const float* desc1 = (const float*)d_in[1];
  const int* corr0   = (const int*)d_in[2];
  const int* corr1   = (const int*)d_in[3];
  const float* lg0   = (const float*)d_in[4];
  const float* lg1   = (const float*)d_in[5];
  float* out = (float*)d_out;

  char* w = (char*)d_ws;
  short* d0b   = (short*)(w);                   // 3,145,728 B
  short* d1b   = (short*)(w + 3145728);         // 3,145,728 B
  uint2* colKV = (uint2*)(w + 6291456);         //  9,437,184 B  [96][12288]
  uint2* rowKV = (uint2*)(w + 15728640);        //  1,572,864 B  [16][12288]
  unsigned* best0 = (unsigned*)(w + 17301504);  //     49,152 B
  unsigned* best1 = (unsigned*)(w + 17350656);  //     49,152 B
  float* l0part = (float*)(w + 17399808);       //        192 B
  float* l1part = (float*)(w + 17400000);       //        192 B
  int4* statpart = (int4*)(w + 17400192);       //        768 B

  k_conv<<<3072, 256, 0, stream>>>(desc0, desc1, d0b, d1b);
  k_main<<<1536, 256, 0, stream>>>(d0b, d1b, colKV, rowKV);
  k_red<<<96, 256, 0, stream>>>(colKV, rowKV, desc0, desc1, corr0, corr1, best0, best1, l0part, l1part);
  k_stats<<<48, 256, 0, stream>>>(corr0, corr1, lg0, lg1, best0, best1, statpart);
  k_final<<<1, 64, 0, stream>>>(l0part, l1part, statpart, out);
}